// Round 1
// baseline (415.679 us; speedup 1.0000x reference)
//
#include <hip/hip_runtime.h>
#include <cstdint>
#include <cstddef>

// Problem constants (NonLocalBlock: B=4, C=128, H=W=64)
#define B_   4
#define C_   128
#define HW_  4096

typedef _Float16 h16;
typedef _Float16 h16x8 __attribute__((ext_vector_type(8)));
typedef float f32x4v __attribute__((ext_vector_type(4)));
typedef float f32x16v __attribute__((ext_vector_type(16)));

static __device__ __forceinline__ uint32_t cvtpk(float x, float y) {
  // v_cvt_pkrtz_f16_f32: low half <- x, high half <- y
  auto h = __builtin_amdgcn_cvt_pkrtz(x, y);
  return __builtin_bit_cast(uint32_t, h);
}

static __device__ __forceinline__ void gload_lds16(const void* g, void* l) {
  // async global->LDS, 16B per lane; LDS dest = wave-uniform base + lane*16
  __builtin_amdgcn_global_load_lds((const __attribute__((address_space(1))) uint32_t*)g,
                                   (__attribute__((address_space(3))) uint32_t*)l, 16, 0, 0);
}

// ---------------------------------------------------------------------------
// Kernel 1: 1x1-conv projections + (for q,k) channel mean-sub + L2 normalize,
// emit fp16: pq/pk as [B*HW][C] (pixel-major), pv as [B][C][HW] (channel-major).
// Grid: (256 pixel-tiles of 64, 3 projections). Block 256 threads.
// f32 math throughout; only the final store is fp16.
// ---------------------------------------------------------------------------
__global__ __launch_bounds__(256) void proj_kernel(
    const float* __restrict__ qimg, const float* __restrict__ kimg, const float* __restrict__ vimg,
    const float* __restrict__ Wq, const float* __restrict__ bq,
    const float* __restrict__ Wk, const float* __restrict__ bk,
    const float* __restrict__ Wv, const float* __restrict__ bv,
    h16* __restrict__ pq, h16* __restrict__ pk, h16* __restrict__ pv)
{
  // LDS: staging (W chunk [128][33] = 16896B, x chunk [32][72] = 9216B) aliased
  // with ps [128][72] (36864B) used for the normalization pass.
  __shared__ __align__(16) float sm[9216];
  float* wch = sm;                 // [128][33]
  float* xs  = sm + 4224;          // [32][72]
  float* ps  = sm;                 // [128][72] (alias, used after GEMM loop)

  const int tid   = threadIdx.x;
  const int which = blockIdx.y;            // 0=q, 1=k, 2=v
  const int p0g   = blockIdx.x * 64;       // global pixel (b*HW + p)
  const int b     = p0g >> 12;
  const int p0    = p0g & (HW_ - 1);

  const float* x; const float* W; const float* bias;
  if      (which == 0) { x = qimg; W = Wq; bias = bq; }
  else if (which == 1) { x = kimg; W = Wk; bias = bk; }
  else                 { x = vimg; W = Wv; bias = bv; }
  const float* xb = x + (size_t)b * C_ * HW_ + p0;

  const int ogrp = tid >> 3;   // 0..31 -> 4 output channels each
  const int pgrp = tid & 7;    // 0..7  -> 8 pixels each
  const int obase = ogrp * 4, pbase = pgrp * 8;

  float acc[4][8];
  #pragma unroll
  for (int i = 0; i < 4; ++i) {
    const float bi = bias[obase + i];
    #pragma unroll
    for (int j = 0; j < 8; ++j) acc[i][j] = bi;
  }

  for (int s = 0; s < 4; ++s) {            // K chunks of 32
    #pragma unroll
    for (int it = 0; it < 16; ++it) {      // W chunk: 128x32
      const int idx = tid + it * 256;
      const int o = idx >> 5, kc = idx & 31;
      wch[o * 33 + kc] = W[o * 128 + s * 32 + kc];
    }
    #pragma unroll
    for (int it = 0; it < 8; ++it) {       // x chunk: 32x64
      const int idx = tid + it * 256;
      const int c = idx >> 6, p = idx & 63;
      xs[c * 72 + p] = xb[(size_t)(s * 32 + c) * HW_ + p];
    }
    __syncthreads();
    #pragma unroll 4
    for (int k = 0; k < 32; ++k) {
      const float4 xv0 = *(const float4*)&xs[k * 72 + pbase];
      const float4 xv1 = *(const float4*)&xs[k * 72 + pbase + 4];
      #pragma unroll
      for (int i = 0; i < 4; ++i) {
        const float wv_ = wch[(obase + i) * 33 + k];
        acc[i][0] += wv_ * xv0.x; acc[i][1] += wv_ * xv0.y;
        acc[i][2] += wv_ * xv0.z; acc[i][3] += wv_ * xv0.w;
        acc[i][4] += wv_ * xv1.x; acc[i][5] += wv_ * xv1.y;
        acc[i][6] += wv_ * xv1.z; acc[i][7] += wv_ * xv1.w;
      }
    }
    __syncthreads();
  }

  if (which == 2) {
    // pv: raw projection, [B][C][HW] layout (PV GEMM wants m contiguous per c)
    h16* dst = pv + (size_t)b * C_ * HW_ + p0;
    #pragma unroll
    for (int i = 0; i < 4; ++i) {
      h16x8 hv;
      #pragma unroll
      for (int j = 0; j < 8; ++j) hv[j] = (h16)acc[i][j];
      *(h16x8*)(dst + (size_t)(obase + i) * HW_ + pbase) = hv;
    }
    return;
  }

  // q/k: per-pixel channel mean-sub + L2 normalize. Round-trip through LDS.
  #pragma unroll
  for (int i = 0; i < 4; ++i) {
    float4 v0 = { acc[i][0], acc[i][1], acc[i][2], acc[i][3] };
    float4 v1 = { acc[i][4], acc[i][5], acc[i][6], acc[i][7] };
    *(float4*)&ps[(obase + i) * 72 + pbase]     = v0;
    *(float4*)&ps[(obase + i) * 72 + pbase + 4] = v1;
  }
  __syncthreads();

  const int pr = tid >> 2;   // pixel 0..63
  const int part = tid & 3;  // 4 threads per pixel, 32 channels each
  float sum = 0.f;
  #pragma unroll
  for (int i = 0; i < 32; ++i) sum += ps[(part * 32 + i) * 72 + pr];
  sum += __shfl_xor(sum, 1, 64);
  sum += __shfl_xor(sum, 2, 64);
  const float mean = sum * (1.0f / 128.0f);
  float ssq = 0.f;
  #pragma unroll
  for (int i = 0; i < 32; ++i) {
    const float d = ps[(part * 32 + i) * 72 + pr] - mean;
    ssq += d * d;
  }
  ssq += __shfl_xor(ssq, 1, 64);
  ssq += __shfl_xor(ssq, 2, 64);
  const float inv = 1.0f / sqrtf(ssq);

  h16* dst = (which == 0 ? pq : pk) + (size_t)(p0g + pr) * C_ + part * 32;
  #pragma unroll
  for (int i8 = 0; i8 < 4; ++i8) {
    h16x8 hv;
    #pragma unroll
    for (int j = 0; j < 8; ++j)
      hv[j] = (h16)((ps[(part * 32 + i8 * 8 + j) * 72 + pr] - mean) * inv);
    *(h16x8*)(dst + i8 * 8) = hv;
  }
}

// ---------------------------------------------------------------------------
// Kernel 2: fused flash-style attention.
//   corr[b,n,m] = pq[n,:]·pk[m,:]  (written out, 268MB — the HBM floor)
//   conf[b,n]   = max_m corr
//   out[b,c,n]  = gamma * (pv @ softmax(corr/tau)^T) + value_img
// 256 blocks (1/CU), 4 waves. Block owns 64 n-rows; wave (mi,nj) owns n-half
// nj and m-chunk mi of each 64-m tile; online softmax per wave, merged once
// at the epilogue. Swapped QK^T (A=pk, B=pq) keeps the P-column lane-local;
// cvt_pkrtz + permlane32_swap builds PV B-fragments fully in-register.
// LDS 64KB: double-buffered kt[64][128] + vt[128][64] fp16, XOR-swizzled via
// pre-swizzled global_load_lds sources (same involution on the read side).
// ---------------------------------------------------------------------------
__global__ __launch_bounds__(256, 1) void attn_kernel(
    const h16* __restrict__ pqg, const h16* __restrict__ pkg, const h16* __restrict__ pvg,
    const float* __restrict__ vimg, const float* __restrict__ gp, const float* __restrict__ taup,
    float* __restrict__ corr, float* __restrict__ conf, float* __restrict__ outp)
{
  __shared__ __align__(128) char smem[65536];

  const int tid  = threadIdx.x;
  const int wv   = tid >> 6;     // wave 0..3
  const int lane = tid & 63;
  const int l31  = lane & 31;
  const int hi   = lane >> 5;
  const int mi   = wv & 1;       // m-chunk within 64-m tile
  const int nj   = wv >> 1;      // n-half within 64-n block

  // XCD-aware mapping: blocks land round-robin on 8 XCDs; give each XCD one
  // batch so pk/pv/pq (3MB) stay resident in that XCD's 4MB L2.
  const int bx    = blockIdx.x;
  const int b     = (bx & 7) >> 1;
  const int ntile = ((bx >> 3) << 1) | (bx & 1);
  const int n0    = ntile * 64;

  const float tau   = taup[0];
  const float gamma = gp[0];
  const float kl    = 1.44269504088896340736f / tau;   // log2(e)/tau

  // persistent Q fragments (B-operand): lane holds col n = l31 (+nj*32)
  h16x8 qf[8];
  {
    const h16* qrow = pqg + ((size_t)(b * HW_ + n0 + nj * 32 + l31)) * C_ + hi * 8;
    #pragma unroll
    for (int kc = 0; kc < 8; ++kc) qf[kc] = *(const h16x8*)(qrow + kc * 16);
  }

  f32x16v oacc[4];   // O^T [c=cs*32+crow][n=l31+nj*32], 4 c-subtiles
  #pragma unroll
  for (int i = 0; i < 4; ++i) oacc[i] = (f32x16v)0.0f;
  float m_run = -3.0e38f, l_run = 0.0f;

  const char* pkb = (const char*)(pkg + (size_t)b * HW_ * C_);
  const char* pvb = (const char*)(pvg + (size_t)b * C_ * HW_);

  // per-lane staging offsets (pre-swizzled sources; rule 21: same XOR on read)
  size_t ktoff[4], vtoff[4];
  #pragma unroll
  for (int c4 = 0; c4 < 4; ++c4) {
    const int ch = wv * 4 + c4;
    const int mm = ch * 4 + (lane >> 4);
    const int cb = (lane & 15) * 16;
    ktoff[c4] = (size_t)mm * 256 + (size_t)(cb ^ ((mm & 15) << 4));
    const int cc = ch * 8 + (lane >> 3);
    const int mb = (lane & 7) * 16;
    vtoff[c4] = (size_t)cc * 8192 + (size_t)(mb ^ ((cc & 7) << 4));
  }

  auto STAGE = [&](int tt) {
    const int buf = tt & 1;
    char* ktb = smem + buf * 16384;
    char* vtb = smem + 32768 + buf * 16384;
    const size_t kbase = (size_t)tt * 16384;  // 64 rows * 256B
    const size_t vbase = (size_t)tt * 128;    // 64 m * 2B within each c-row
    #pragma unroll
    for (int c4 = 0; c4 < 4; ++c4) {
      const int ch = wv * 4 + c4;
      gload_lds16(pkb + kbase + ktoff[c4], ktb + ch * 1024);
    }
    #pragma unroll
    for (int c4 = 0; c4 < 4; ++c4) {
      const int ch = wv * 4 + c4;
      gload_lds16(pvb + vbase + vtoff[c4], vtb + ch * 1024);
    }
  };

  STAGE(0);
  asm volatile("s_waitcnt vmcnt(0)" ::: "memory");
  __builtin_amdgcn_s_barrier();

  for (int t = 0; t < HW_ / 64; ++t) {
    if (t < HW_ / 64 - 1) STAGE(t + 1);   // prefetch next tile into other buffer

    const int buf = t & 1;
    const char* ktb = smem + buf * 16384;
    const char* vtb = smem + 32768 + buf * 16384;

    // ---- QK^T (swapped: A = pk rows m, B = pq cols n) ----
    f32x16v sacc = (f32x16v)0.0f;
    {
      const int mrow = mi * 32 + l31;
      const char* arow = ktb + mrow * 256;
      const int swz = (mrow & 15) << 4;
      #pragma unroll
      for (int kc = 0; kc < 8; ++kc) {
        const h16x8 af = *(const h16x8*)(arow + ((kc * 32 + hi * 16) ^ swz));
        sacc = __builtin_amdgcn_mfma_f32_32x32x16_f16(af, qf[kc], sacc, 0, 0, 0);
      }
    }

    // ---- corr_map stores: lane holds col n, rows m = (r&3)+8*(r>>2)+4*hi ----
    {
      float* cr = corr + (size_t)(b * HW_ + n0 + nj * 32 + l31) * HW_
                + t * 64 + mi * 32 + hi * 4;
      #pragma unroll
      for (int rq = 0; rq < 4; ++rq) {
        f32x4v v = { sacc[rq * 4 + 0], sacc[rq * 4 + 1], sacc[rq * 4 + 2], sacc[rq * 4 + 3] };
        *(f32x4v*)(cr + rq * 8) = v;
      }
    }

    // ---- online softmax (per-lane column; one cross-half exchange) ----
    float tm = sacc[0];
    #pragma unroll
    for (int r = 1; r < 16; ++r) tm = fmaxf(tm, sacc[r]);
    tm = fmaxf(tm, __shfl_xor(tm, 32, 64));
    const float mnew  = fmaxf(m_run, tm);
    const float scale = __builtin_exp2f((m_run - mnew) * kl);
    const float mk    = mnew * kl;
    float ps[16]; float rs = 0.f;
    #pragma unroll
    for (int r = 0; r < 16; ++r) { ps[r] = __builtin_exp2f(sacc[r] * kl - mk); rs += ps[r]; }
    rs += __shfl_xor(rs, 32, 64);
    l_run = l_run * scale + rs;
    m_run = mnew;
    #pragma unroll
    for (int i = 0; i < 4; ++i) oacc[i] *= scale;

    // ---- P -> fp16 B-fragments in-register (cvt_pkrtz + permlane32_swap) ----
    h16x8 pf[2];
    #pragma unroll
    for (int k2 = 0; k2 < 2; ++k2) {
      const int bs = k2 * 8;
      uint32_t a = cvtpk(ps[bs + 0], ps[bs + 1]);
      uint32_t bb = cvtpk(ps[bs + 2], ps[bs + 3]);
      uint32_t c = cvtpk(ps[bs + 4], ps[bs + 5]);
      uint32_t d = cvtpk(ps[bs + 6], ps[bs + 7]);
      asm("v_permlane32_swap_b32 %0, %1" : "+v"(a), "+v"(c));
      asm("v_permlane32_swap_b32 %0, %1" : "+v"(bb), "+v"(d));
      union { uint32_t w[4]; h16x8 h; } u;
      u.w[0] = a; u.w[1] = bb; u.w[2] = c; u.w[3] = d;
      pf[k2] = u.h;
    }

    // ---- PV: O^T[c][n] += pv^T[c][m] * P^T[m][n] ----
    #pragma unroll
    for (int k2 = 0; k2 < 2; ++k2) {
      #pragma unroll
      for (int cs = 0; cs < 4; ++cs) {
        const int crw = cs * 32 + l31;
        const char* vrow = vtb + crw * 128;
        const int mb = (mi * 64 + k2 * 32 + hi * 16) ^ ((crw & 7) << 4);
        const h16x8 vf = *(const h16x8*)(vrow + mb);
        oacc[cs] = __builtin_amdgcn_mfma_f32_32x32x16_f16(vf, pf[k2], oacc[cs], 0, 0, 0);
      }
    }

    asm volatile("s_waitcnt vmcnt(0)" ::: "memory");
    __builtin_amdgcn_s_barrier();
  }

  // ---- epilogue: merge the two m-partitions per n-half, write conf & out ----
  float* ms  = (float*)(smem + 32768);          // [4][32]
  float* ls  = (float*)(smem + 32768 + 512);    // [4][32]
  float* lgi = (float*)(smem + 32768 + 1024);   // [2][32]

  if (lane < 32) { ms[wv * 32 + l31] = m_run; ls[wv * 32 + l31] = l_run; }
  __syncthreads();

  const float m0v = ms[nj * 64 + l31], m1v = ms[nj * 64 + 32 + l31];
  const float mg  = fmaxf(m0v, m1v);
  const float lg  = ls[nj * 64 + l31]      * __builtin_exp2f((m0v - mg) * kl)
                  + ls[nj * 64 + 32 + l31] * __builtin_exp2f((m1v - mg) * kl);
  const float fw  = __builtin_exp2f((m_run - mg) * kl);
  if (mi == 0 && lane < 32) {
    lgi[nj * 32 + l31] = 1.0f / lg;
    conf[(size_t)b * HW_ + n0 + nj * 32 + l31] = mg;
  }
  __syncthreads();

  float* otb = (float*)smem;   // [mi 2][nj 2][c 64][n 32] per pass
  #pragma unroll
  for (int p = 0; p < 2; ++p) {
    #pragma unroll
    for (int csl = 0; csl < 2; ++csl) {
      const int cs = p * 2 + csl;
      #pragma unroll
      for (int r = 0; r < 16; ++r) {
        const int cl = ((r & 3) + 8 * (r >> 2) + 4 * hi) + csl * 32;
        otb[((mi * 2 + nj) * 64 + cl) * 32 + l31] = oacc[cs][r] * fw;
      }
    }
    __syncthreads();
    {
      const int n = tid & 31;
      const int rsel = tid >> 5;   // 0..7
      #pragma unroll
      for (int i = 0; i < 16; ++i) {
        const int R = rsel + i * 8;        // 0..127
        const int nj2 = R >> 6, cl = R & 63;
        const int c = p * 64 + cl;
        const float sum = otb[((0 * 2 + nj2) * 64 + cl) * 32 + n]
                        + otb[((1 * 2 + nj2) * 64 + cl) * 32 + n];
        const size_t gi = ((size_t)(b * C_ + c)) * HW_ + n0 + nj2 * 32 + n;
        outp[gi] = gamma * sum * lgi[nj2 * 32 + n] + vimg[gi];
      }
    }
    __syncthreads();
  }
}

// ---------------------------------------------------------------------------
extern "C" void kernel_launch(void* const* d_in, const int* in_sizes, int n_in,
                              void* d_out, int out_size, void* d_ws, size_t ws_size,
                              hipStream_t stream) {
  const float* kimg = (const float*)d_in[0];
  const float* qimg = (const float*)d_in[1];
  const float* vimg = (const float*)d_in[2];
  const float* Wq   = (const float*)d_in[3];
  const float* bq   = (const float*)d_in[4];
  const float* Wk   = (const float*)d_in[5];
  const float* bk   = (const float*)d_in[6];
  const float* Wv   = (const float*)d_in[7];
  const float* bv   = (const float*)d_in[8];
  const float* gam  = (const float*)d_in[9];
  const float* tau  = (const float*)d_in[10];

  float* corr = (float*)d_out;                            // [B][HW][HW]
  float* conf = corr + (size_t)B_ * HW_ * HW_;            // [B][HW]
  float* outp = conf + (size_t)B_ * HW_;                  // [B][C][HW]

  h16* pq = (h16*)d_ws;                                   // [B*HW][C]
  h16* pk = pq + (size_t)B_ * HW_ * C_;                   // [B*HW][C]
  h16* pv = pk + (size_t)B_ * HW_ * C_;                   // [B][C][HW]

  proj_kernel<<<dim3(B_ * HW_ / 64, 3, 1), 256, 0, stream>>>(
      qimg, kimg, vimg, Wq, bq, Wk, bk, Wv, bv, pq, pk, pv);
  attn_kernel<<<dim3(256, 1, 1), 256, 0, stream>>>(
      pq, pk, pv, vimg, gam, tau, corr, conf, outp);
}

// Round 2
// 380.629 us; speedup vs baseline: 1.0921x; 1.0921x over previous
//
#include <hip/hip_runtime.h>
#include <cstdint>
#include <cstddef>

// Problem constants (NonLocalBlock: B=4, C=128, H=W=64)
#define B_   4
#define C_   128
#define HW_  4096

typedef _Float16 h16;
typedef _Float16 h16x8 __attribute__((ext_vector_type(8)));
typedef float f32x4v __attribute__((ext_vector_type(4)));
typedef float f32x16v __attribute__((ext_vector_type(16)));

static __device__ __forceinline__ uint32_t cvtpk(float x, float y) {
  // v_cvt_pkrtz_f16_f32: low half <- x, high half <- y
  auto h = __builtin_amdgcn_cvt_pkrtz(x, y);
  return __builtin_bit_cast(uint32_t, h);
}

static __device__ __forceinline__ void gload_lds16(const void* g, void* l) {
  // async global->LDS, 16B per lane; LDS dest = wave-uniform base + lane*16
  __builtin_amdgcn_global_load_lds((const __attribute__((address_space(1))) uint32_t*)g,
                                   (__attribute__((address_space(3))) uint32_t*)l, 16, 0, 0);
}

// ---------------------------------------------------------------------------
// Kernel 1: 1x1-conv projections + (for q,k) channel mean-sub + L2 normalize,
// emit fp16: pq/pk as [B*HW][C] (pixel-major), pv as [B][C][HW] (channel-major).
// (unchanged from round 1 — passed; attn is the bottleneck this round)
// ---------------------------------------------------------------------------
__global__ __launch_bounds__(256) void proj_kernel(
    const float* __restrict__ qimg, const float* __restrict__ kimg, const float* __restrict__ vimg,
    const float* __restrict__ Wq, const float* __restrict__ bq,
    const float* __restrict__ Wk, const float* __restrict__ bk,
    const float* __restrict__ Wv, const float* __restrict__ bv,
    h16* __restrict__ pq, h16* __restrict__ pk, h16* __restrict__ pv)
{
  __shared__ __align__(16) float sm[9216];
  float* wch = sm;                 // [128][33]
  float* xs  = sm + 4224;          // [32][72]
  float* ps  = sm;                 // [128][72] (alias, used after GEMM loop)

  const int tid   = threadIdx.x;
  const int which = blockIdx.y;            // 0=q, 1=k, 2=v
  const int p0g   = blockIdx.x * 64;       // global pixel (b*HW + p)
  const int b     = p0g >> 12;
  const int p0    = p0g & (HW_ - 1);

  const float* x; const float* W; const float* bias;
  if      (which == 0) { x = qimg; W = Wq; bias = bq; }
  else if (which == 1) { x = kimg; W = Wk; bias = bk; }
  else                 { x = vimg; W = Wv; bias = bv; }
  const float* xb = x + (size_t)b * C_ * HW_ + p0;

  const int ogrp = tid >> 3;   // 0..31 -> 4 output channels each
  const int pgrp = tid & 7;    // 0..7  -> 8 pixels each
  const int obase = ogrp * 4, pbase = pgrp * 8;

  float acc[4][8];
  #pragma unroll
  for (int i = 0; i < 4; ++i) {
    const float bi = bias[obase + i];
    #pragma unroll
    for (int j = 0; j < 8; ++j) acc[i][j] = bi;
  }

  for (int s = 0; s < 4; ++s) {            // K chunks of 32
    #pragma unroll
    for (int it = 0; it < 16; ++it) {      // W chunk: 128x32
      const int idx = tid + it * 256;
      const int o = idx >> 5, kc = idx & 31;
      wch[o * 33 + kc] = W[o * 128 + s * 32 + kc];
    }
    #pragma unroll
    for (int it = 0; it < 8; ++it) {       // x chunk: 32x64
      const int idx = tid + it * 256;
      const int c = idx >> 6, p = idx & 63;
      xs[c * 72 + p] = xb[(size_t)(s * 32 + c) * HW_ + p];
    }
    __syncthreads();
    #pragma unroll 4
    for (int k = 0; k < 32; ++k) {
      const float4 xv0 = *(const float4*)&xs[k * 72 + pbase];
      const float4 xv1 = *(const float4*)&xs[k * 72 + pbase + 4];
      #pragma unroll
      for (int i = 0; i < 4; ++i) {
        const float wv_ = wch[(obase + i) * 33 + k];
        acc[i][0] += wv_ * xv0.x; acc[i][1] += wv_ * xv0.y;
        acc[i][2] += wv_ * xv0.z; acc[i][3] += wv_ * xv0.w;
        acc[i][4] += wv_ * xv1.x; acc[i][5] += wv_ * xv1.y;
        acc[i][6] += wv_ * xv1.z; acc[i][7] += wv_ * xv1.w;
      }
    }
    __syncthreads();
  }

  if (which == 2) {
    h16* dst = pv + (size_t)b * C_ * HW_ + p0;
    #pragma unroll
    for (int i = 0; i < 4; ++i) {
      h16x8 hv;
      #pragma unroll
      for (int j = 0; j < 8; ++j) hv[j] = (h16)acc[i][j];
      *(h16x8*)(dst + (size_t)(obase + i) * HW_ + pbase) = hv;
    }
    return;
  }

  #pragma unroll
  for (int i = 0; i < 4; ++i) {
    float4 v0 = { acc[i][0], acc[i][1], acc[i][2], acc[i][3] };
    float4 v1 = { acc[i][4], acc[i][5], acc[i][6], acc[i][7] };
    *(float4*)&ps[(obase + i) * 72 + pbase]     = v0;
    *(float4*)&ps[(obase + i) * 72 + pbase + 4] = v1;
  }
  __syncthreads();

  const int pr = tid >> 2;   // pixel 0..63
  const int part = tid & 3;  // 4 threads per pixel, 32 channels each
  float sum = 0.f;
  #pragma unroll
  for (int i = 0; i < 32; ++i) sum += ps[(part * 32 + i) * 72 + pr];
  sum += __shfl_xor(sum, 1, 64);
  sum += __shfl_xor(sum, 2, 64);
  const float mean = sum * (1.0f / 128.0f);
  float ssq = 0.f;
  #pragma unroll
  for (int i = 0; i < 32; ++i) {
    const float d = ps[(part * 32 + i) * 72 + pr] - mean;
    ssq += d * d;
  }
  ssq += __shfl_xor(ssq, 1, 64);
  ssq += __shfl_xor(ssq, 2, 64);
  const float inv = 1.0f / sqrtf(ssq);

  h16* dst = (which == 0 ? pq : pk) + (size_t)(p0g + pr) * C_ + part * 32;
  #pragma unroll
  for (int i8 = 0; i8 < 4; ++i8) {
    h16x8 hv;
    #pragma unroll
    for (int j = 0; j < 8; ++j)
      hv[j] = (h16)((ps[(part * 32 + i8 * 8 + j) * 72 + pr] - mean) * inv);
    *(h16x8*)(dst + i8 * 8) = hv;
  }
}

// ---------------------------------------------------------------------------
// Kernel 2: fused flash-style attention, v2.
//   256 blocks x 512 threads (8 waves = 2/SIMD). Block owns 64 n-rows;
//   wave (mi in 0..3, nj in 0..1) owns m-chunk mi of each 128-m tile and
//   n-half nj. 32 iterations. LDS 128KB: dbuf kt[128][256B] + vt[128][256B],
//   XOR-swizzled via pre-swizzled global_load_lds sources.
//   Counted s_waitcnt vmcnt(4) at loop bottom: waits the 8 prefetch
//   global_load_lds, lets the 4 newest corr stores drain across the barrier
//   (write-drain paces the loop = the HBM floor). Defer-max rescale (T13).
// ---------------------------------------------------------------------------
__global__ __launch_bounds__(512, 2) void attn_kernel(
    const h16* __restrict__ pqg, const h16* __restrict__ pkg, const h16* __restrict__ pvg,
    const float* __restrict__ vimg, const float* __restrict__ gp, const float* __restrict__ taup,
    float* __restrict__ corr, float* __restrict__ conf, float* __restrict__ outp)
{
  __shared__ __align__(128) char smem[131072];   // kt dbuf 64KB + vt dbuf 64KB
  __shared__ float ms[8 * 32], ls[8 * 32], tms[8 * 32], lgi[2 * 32];

  const int tid  = threadIdx.x;
  const int wv   = tid >> 6;     // wave 0..7
  const int lane = tid & 63;
  const int l31  = lane & 31;
  const int hi   = lane >> 5;
  const int mi   = wv & 3;       // m-chunk within 128-m tile
  const int nj   = wv >> 2;      // n-half within 64-n block

  // XCD-aware mapping: each XCD serves one batch (pk/pv/pq stay L2-resident)
  const int bx    = blockIdx.x;
  const int b     = (bx & 7) >> 1;
  const int ntile = ((bx >> 3) << 1) | (bx & 1);
  const int n0    = ntile * 64;

  const float tau   = taup[0];
  const float gamma = gp[0];
  const float kl    = 1.44269504088896340736f / tau;   // log2(e)/tau

  // persistent Q fragments (B-operand): lane holds col n = l31 (+nj*32)
  h16x8 qf[8];
  {
    const h16* qrow = pqg + ((size_t)(b * HW_ + n0 + nj * 32 + l31)) * C_ + hi * 8;
    #pragma unroll
    for (int kc = 0; kc < 8; ++kc) qf[kc] = *(const h16x8*)(qrow + kc * 16);
  }

  f32x16v oacc[4];   // O^T [c=cs*32+crw][n], this wave's mi-partition
  #pragma unroll
  for (int i = 0; i < 4; ++i) oacc[i] = (f32x16v)0.0f;
  float m_run = -3.0e38f, l_run = 0.0f, tmax = -3.0e38f;

  const char* pkb = (const char*)(pkg + (size_t)b * HW_ * C_);
  const char* pvb = (const char*)(pvg + (size_t)b * C_ * HW_);

  // per-lane staging offsets (pre-swizzled sources; same XOR on the read side)
  size_t ktoff[4], vtoff[4];
  #pragma unroll
  for (int c4 = 0; c4 < 4; ++c4) {
    const int ch = wv * 4 + c4;               // chunk 0..31 (1KB each)
    const int mm = ch * 4 + (lane >> 4);      // kt row 0..127
    const int cb = (lane & 15) * 16;          // byte within 256B row
    ktoff[c4] = (size_t)mm * 256 + (size_t)(cb ^ ((mm & 15) << 4));
    const int cc = ch * 4 + (lane >> 4);      // vt row (channel) 0..127
    const int xb2 = (lane & 15) * 16;         // byte within 256B tile-row
    vtoff[c4] = (size_t)cc * 8192 + (size_t)(xb2 ^ ((cc & 15) << 4));
  }

  auto STAGE = [&](int tt) {
    const int buf = tt & 1;
    char* ktb = smem + buf * 32768;
    char* vtb = smem + 65536 + buf * 32768;
    const size_t kbase = (size_t)tt * 32768;  // 128 rows * 256B
    const size_t vbase = (size_t)tt * 256;    // 128 m * 2B within each c-row
    #pragma unroll
    for (int c4 = 0; c4 < 4; ++c4) {
      const int ch = wv * 4 + c4;
      gload_lds16(pkb + kbase + ktoff[c4], ktb + ch * 1024);
      gload_lds16(pvb + vbase + vtoff[c4], vtb + ch * 1024);
    }
  };

  STAGE(0);
  asm volatile("s_waitcnt vmcnt(0)" ::: "memory");
  __builtin_amdgcn_s_barrier();

  for (int t = 0; t < HW_ / 128; ++t) {
    if (t < HW_ / 128 - 1) STAGE(t + 1);   // prefetch next tile, other buffer

    const int buf = t & 1;
    const char* ktb = smem + buf * 32768;
    const char* vtb = smem + 65536 + buf * 32768;

    // ---- QK^T (swapped: A = pk rows m, B = pq cols n) ----
    f32x16v sacc = (f32x16v)0.0f;
    {
      const int mrow = mi * 32 + l31;
      const char* arow = ktb + mrow * 256;
      const int swz = (mrow & 15) << 4;
      __builtin_amdgcn_s_setprio(1);
      #pragma unroll
      for (int kc = 0; kc < 8; ++kc) {
        const h16x8 af = *(const h16x8*)(arow + ((kc * 32 + hi * 16) ^ swz));
        sacc = __builtin_amdgcn_mfma_f32_32x32x16_f16(af, qf[kc], sacc, 0, 0, 0);
      }
      __builtin_amdgcn_s_setprio(0);
    }

    // ---- corr_map stores: lane holds col n, rows m = (r&3)+8*(r>>2)+4*hi ----
    {
      float* cr = corr + (size_t)(b * HW_ + n0 + nj * 32 + l31) * HW_
                + t * 128 + mi * 32 + hi * 4;
      #pragma unroll
      for (int rq = 0; rq < 4; ++rq) {
        f32x4v v = { sacc[rq * 4 + 0], sacc[rq * 4 + 1], sacc[rq * 4 + 2], sacc[rq * 4 + 3] };
        *(f32x4v*)(cr + rq * 8) = v;
      }
    }

    // ---- online softmax (per-lane column; one cross-half exchange) ----
    float tm = sacc[0];
    #pragma unroll
    for (int r = 1; r < 16; ++r) tm = fmaxf(tm, sacc[r]);
    tm = fmaxf(tm, __shfl_xor(tm, 32, 64));
    tmax = fmaxf(tmax, tm);
    const float mnew = fmaxf(m_run, tm);
    if (__any((mnew - m_run) * kl > 8.0f)) {   // defer-max: rescale only on real growth
      const float scale = __builtin_exp2f((m_run - mnew) * kl);
      #pragma unroll
      for (int i = 0; i < 4; ++i) oacc[i] *= scale;
      l_run *= scale;
      m_run = mnew;
    }
    const float mk = m_run * kl;
    float ps[16]; float rs = 0.f;
    #pragma unroll
    for (int r = 0; r < 16; ++r) { ps[r] = __builtin_exp2f(sacc[r] * kl - mk); rs += ps[r]; }
    rs += __shfl_xor(rs, 32, 64);
    l_run += rs;

    // ---- P -> fp16 B-fragments in-register (cvt_pkrtz + permlane32_swap) ----
    h16x8 pf[2];
    #pragma unroll
    for (int k2 = 0; k2 < 2; ++k2) {
      const int bs = k2 * 8;
      uint32_t a = cvtpk(ps[bs + 0], ps[bs + 1]);
      uint32_t bb = cvtpk(ps[bs + 2], ps[bs + 3]);
      uint32_t c = cvtpk(ps[bs + 4], ps[bs + 5]);
      uint32_t d = cvtpk(ps[bs + 6], ps[bs + 7]);
      asm("v_permlane32_swap_b32 %0, %1" : "+v"(a), "+v"(c));
      asm("v_permlane32_swap_b32 %0, %1" : "+v"(bb), "+v"(d));
      union { uint32_t w[4]; h16x8 h; } u;
      u.w[0] = a; u.w[1] = bb; u.w[2] = c; u.w[3] = d;
      pf[k2] = u.h;
    }

    // ---- PV: O^T[c][n] += pv^T[c][m-slice] * P^T[m-slice][n] ----
    __builtin_amdgcn_s_setprio(1);
    #pragma unroll
    for (int k2 = 0; k2 < 2; ++k2) {
      #pragma unroll
      for (int cs = 0; cs < 4; ++cs) {
        const int crw = cs * 32 + l31;
        const char* vrow = vtb + crw * 256;
        const int mb = (mi * 64 + k2 * 32 + hi * 16) ^ ((crw & 15) << 4);
        const h16x8 vf = *(const h16x8*)(vrow + mb);
        oacc[cs] = __builtin_amdgcn_mfma_f32_32x32x16_f16(vf, pf[k2], oacc[cs], 0, 0, 0);
      }
    }
    __builtin_amdgcn_s_setprio(0);

    // wait the 8 prefetch loads (and older stores); let newest 4 stores fly
    asm volatile("s_waitcnt vmcnt(4)" ::: "memory");
    __builtin_amdgcn_s_barrier();
  }

  // ---- epilogue: merge the 4 m-partitions per n-half, write conf & out ----
  if (lane < 32) {
    ms[wv * 32 + l31] = m_run; ls[wv * 32 + l31] = l_run; tms[wv * 32 + l31] = tmax;
  }
  __syncthreads();

  float mg = ms[(nj * 4 + 0) * 32 + l31];
  float tg = tms[(nj * 4 + 0) * 32 + l31];
  #pragma unroll
  for (int q = 1; q < 4; ++q) {
    mg = fmaxf(mg, ms[(nj * 4 + q) * 32 + l31]);
    tg = fmaxf(tg, tms[(nj * 4 + q) * 32 + l31]);
  }
  float lg = 0.f;
  #pragma unroll
  for (int q = 0; q < 4; ++q)
    lg += ls[(nj * 4 + q) * 32 + l31] * __builtin_exp2f((ms[(nj * 4 + q) * 32 + l31] - mg) * kl);
  const float fw = __builtin_exp2f((m_run - mg) * kl);
  if (mi == 0 && lane < 32) {
    lgi[nj * 32 + l31] = 1.0f / lg;
    conf[(size_t)b * HW_ + n0 + nj * 32 + l31] = tg;
  }

  // otb [mi 4][nj 2][c 128][n 32] f32 = 128KB (reuses smem; main loop done)
  float* otb = (float*)smem;
  #pragma unroll
  for (int cs = 0; cs < 4; ++cs) {
    #pragma unroll
    for (int r = 0; r < 16; ++r) {
      const int cl = ((r & 3) + 8 * (r >> 2) + 4 * hi) + cs * 32;
      otb[((mi * 2 + nj) * 128 + cl) * 32 + l31] = oacc[cs][r] * fw;
    }
  }
  __syncthreads();
  {
    const int n = tid & 31;
    const int rsel = tid >> 5;   // 0..15
    #pragma unroll
    for (int i = 0; i < 16; ++i) {
      const int R = rsel + i * 16;       // 0..255
      const int nj2 = R >> 7, c = R & 127;
      const float sum = otb[((0 * 2 + nj2) * 128 + c) * 32 + n]
                      + otb[((1 * 2 + nj2) * 128 + c) * 32 + n]
                      + otb[((2 * 2 + nj2) * 128 + c) * 32 + n]
                      + otb[((3 * 2 + nj2) * 128 + c) * 32 + n];
      const size_t gi = ((size_t)(b * C_ + c)) * HW_ + n0 + nj2 * 32 + n;
      outp[gi] = gamma * sum * lgi[nj2 * 32 + n] + vimg[gi];
    }
  }
}

// ---------------------------------------------------------------------------
extern "C" void kernel_launch(void* const* d_in, const int* in_sizes, int n_in,
                              void* d_out, int out_size, void* d_ws, size_t ws_size,
                              hipStream_t stream) {
  const float* kimg = (const float*)d_in[0];
  const float* qimg = (const float*)d_in[1];
  const float* vimg = (const float*)d_in[2];
  const float* Wq   = (const float*)d_in[3];
  const float* bq   = (const float*)d_in[4];
  const float* Wk   = (const float*)d_in[5];
  const float* bk   = (const float*)d_in[6];
  const float* Wv   = (const float*)d_in[7];
  const float* bv   = (const float*)d_in[8];
  const float* gam  = (const float*)d_in[9];
  const float* tau  = (const float*)d_in[10];

  float* corr = (float*)d_out;                            // [B][HW][HW]
  float* conf = corr + (size_t)B_ * HW_ * HW_;            // [B][HW]
  float* outp = conf + (size_t)B_ * HW_;                  // [B][C][HW]

  h16* pq = (h16*)d_ws;                                   // [B*HW][C]
  h16* pk = pq + (size_t)B_ * HW_ * C_;                   // [B*HW][C]
  h16* pv = pk + (size_t)B_ * HW_ * C_;                   // [B][C][HW]

  proj_kernel<<<dim3(B_ * HW_ / 64, 3, 1), 256, 0, stream>>>(
      qimg, kimg, vimg, Wq, bq, Wk, bk, Wv, bv, pq, pk, pv);
  attn_kernel<<<dim3(256, 1, 1), 512, 0, stream>>>(
      pq, pk, pv, vimg, gam, tau, corr, conf, outp);
}